// Round 1
// baseline (93.907 us; speedup 1.0000x reference)
//
#include <hip/hip_runtime.h>
#include <math.h>

// StructureLoss: pred [16,2,512,512] f32, mask [16,512,512] f32 -> scalar f32
// loss = mean_b( wbce_b + wiou_b ), weit = 1 + 5*|boxavg31(m) - m|
//
// R6 structure: 512-thread blocks, ONE vertical task per thread (was 1.47 avg,
// max 2 -> barrier straggler). Horizontal 8 px/thread with m/p float4 prefetch
// issued before the vertical phase. Interior blocks (36/64 xy-tiles) take a
// branch-free column-load path. __launch_bounds__(512,4) caps VGPR at 128 so
// 2 blocks (16 waves) stay resident per CU.
#define B_   16
#define H_   512
#define W_   512
#define HW_  (H_ * W_)
#define KR   15
#define KK_INV (1.0f / 961.0f)
#define MU_  5.0f
#define TH   64
#define TW   64
#define HALO_W 94              // TW + 2*KR
#define VSTRIDE 95             // odd stride -> horizontal reads exactly 2-way (free)
#define NTHR 512
#define NVTASK 376             // 4 row-groups x 94 halo cols

// Vertical 31-row sliding sum for one halo column, 16 output rows.
// checked: per-load bounds predication (border tiles only).
__device__ __forceinline__ void vtask_checked(const float* __restrict__ mb,
                                              float* __restrict__ vt,
                                              int task, int r0, int c0)
{
    const int rg = task / HALO_W;
    const int cc = task - rg * HALO_W;
    const int gx = c0 - KR + cc;
    const bool xok = ((unsigned)gx < (unsigned)W_);
    const float* colp = mb + gx;
    const int gy0 = r0 + rg * 16 - KR;
    float keep[15];
    float s = 0.0f;
    #pragma unroll
    for (int d = 0; d < 31; ++d) {
        const int gy = gy0 + d;
        float v = 0.0f;
        if (xok && (unsigned)gy < (unsigned)H_) v = colp[gy * W_];
        if (d < 15) keep[d] = v;
        s += v;
    }
    const int o = (rg * 16) * VSTRIDE + cc;
    vt[o] = s;
    #pragma unroll
    for (int i = 1; i < 16; ++i) {
        const int gy = gy0 + 30 + i;
        float v = 0.0f;
        if (xok && (unsigned)gy < (unsigned)H_) v = colp[gy * W_];
        s += v - keep[i - 1];
        vt[o + i * VSTRIDE] = s;
    }
}

// fast: interior tiles, no bounds checks at all.
__device__ __forceinline__ void vtask_fast(const float* __restrict__ mb,
                                           float* __restrict__ vt,
                                           int task, int r0, int c0)
{
    const int rg = task / HALO_W;
    const int cc = task - rg * HALO_W;
    const float* colp = mb + (c0 - KR + cc) + (r0 + rg * 16 - KR) * W_;
    float keep[15];
    float s = 0.0f;
    #pragma unroll
    for (int d = 0; d < 31; ++d) {
        const float v = colp[d * W_];
        if (d < 15) keep[d] = v;
        s += v;
    }
    const int o = (rg * 16) * VSTRIDE + cc;
    vt[o] = s;
    #pragma unroll
    for (int i = 1; i < 16; ++i) {
        const float v = colp[(30 + i) * W_];
        s += v - keep[i - 1];
        vt[o + i * VSTRIDE] = s;
    }
}

__global__ __launch_bounds__(NTHR, 4) void structure_loss_tile(
    const float* __restrict__ pred,     // [B,2,H,W]
    const float* __restrict__ mask,     // [B,H,W]
    float* __restrict__ partial)        // [1024][4]
{
    __shared__ float vt[TH * VSTRIDE];  // 64 x 95 floats = 24.3 KB
    __shared__ float wsum[8][4];

    const int tid = threadIdx.x;
    const int b   = blockIdx.z;
    const int r0  = blockIdx.y * TH;
    const int c0  = blockIdx.x * TW;
    const int blk = (blockIdx.z * gridDim.y + blockIdx.y) * gridDim.x + blockIdx.x;

    const float* mb = mask + (size_t)b * HW_;
    const float* pb = pred + ((size_t)b * 2 + 1) * HW_;   // channel-1 logits

    // ---- Horizontal-phase coordinates: 8 output px per thread ----
    const int r   = tid >> 3;           // 0..63
    const int ch  = tid & 7;            // 0..7, 8-col chunks
    const int gr  = r0 + r;
    const int gcb = c0 + ch * 8;        // 32B-aligned

    // Prefetch m/p early: independent of the LDS pipeline, HBM latency hides
    // under the vertical column loads.
    const float4* m4 = (const float4*)(mb + gr * W_ + gcb);
    const float4* p4 = (const float4*)(pb + gr * W_ + gcb);
    const float4 ma = m4[0], mc = m4[1];
    const float4 pa = p4[0], pc = p4[1];

    // ---- Vertical phase: one task per thread, balanced ----
    const bool interior = (blockIdx.x >= 1) & (blockIdx.x <= 6) &
                          (blockIdx.y >= 1) & (blockIdx.y <= 6);
    if (tid < NVTASK) {
        if (interior) vtask_fast(mb, vt, tid, r0, c0);
        else          vtask_checked(mb, vt, tid, r0, c0);
    }
    __syncthreads();

    // ---- Horizontal 31-tap slide fused with elementwise math ----
    const int base = r * VSTRIDE + ch * 8;
    float keep[7];
    float s = 0.0f;
    #pragma unroll
    for (int d = 0; d < 31; ++d) {
        const float t = vt[base + d];
        if (d < 7) keep[d] = t;
        s += t;
    }

    float mv[8] = { ma.x, ma.y, ma.z, ma.w, mc.x, mc.y, mc.z, mc.w };
    float pv[8] = { pa.x, pa.y, pa.z, pa.w, pc.x, pc.y, pc.z, pc.w };

    float s_w = 0.0f, s_wb = 0.0f, s_in = 0.0f, s_un = 0.0f;
    #pragma unroll
    for (int j = 0; j < 8; ++j) {
        const float avg = s * KK_INV;
        const float m = mv[j];
        const float p = pv[j];

        const float weit = 1.0f + MU_ * fabsf(avg - m);
        // e = exp(-|p|); bce = max(p,0) - p*m + log(1+e); sigmoid = (p>=0?1:e)/(1+e)
        const float e    = __expf(-fabsf(p));
        const float inv  = __builtin_amdgcn_rcpf(1.0f + e);
        const float bce  = fmaxf(p, 0.0f) - p * m + __logf(1.0f + e);
        const float ps   = (p >= 0.0f ? 1.0f : e) * inv;

        s_w  += weit;
        s_wb += weit * bce;
        s_in += ps * m * weit;
        s_un += (ps + m) * weit;

        if (j < 7)
            s += vt[base + 31 + j] - keep[j];
    }

    // ---- block reduction: wave shuffle -> LDS -> one store per component ----
    const int lane = tid & 63;
    const int wid  = tid >> 6;          // 0..7
    float vals[4] = { s_w, s_wb, s_in, s_un };
    #pragma unroll
    for (int q = 0; q < 4; ++q) {
        float v = vals[q];
        #pragma unroll
        for (int off = 32; off > 0; off >>= 1)
            v += __shfl_down(v, off);
        if (lane == 0) wsum[wid][q] = v;
    }
    __syncthreads();
    if (tid < 4) {
        float tot = 0.0f;
        #pragma unroll
        for (int w = 0; w < 8; ++w) tot += wsum[w][tid];
        partial[blk * 4 + tid] = tot;   // unconditional write -> no memset needed
    }
}

__global__ void structure_loss_final(const float* __restrict__ partial,
                                     float* __restrict__ out)
{
    // 64 threads; 4 threads per batch, 16 float4 blocks each, coalesced.
    const int t = threadIdx.x;
    const float4* p4 = (const float4*)partial;   // one float4 per block
    float4 v = make_float4(0.f, 0.f, 0.f, 0.f);
    #pragma unroll
    for (int j = 0; j < 16; ++j) {
        const float4 q = p4[t * 16 + j];
        v.x += q.x; v.y += q.y; v.z += q.z; v.w += q.w;
    }
    #pragma unroll
    for (int off = 2; off > 0; off >>= 1) {
        v.x += __shfl_down(v.x, off);
        v.y += __shfl_down(v.y, off);
        v.z += __shfl_down(v.z, off);
        v.w += __shfl_down(v.w, off);
    }
    float loss = 0.0f;
    if ((t & 3) == 0) {
        const float sw = v.x, swb = v.y, inter = v.z, uni = v.w;
        loss = swb / sw + 1.0f - (inter + 1.0f) / (uni - inter + 1.0f);
    }
    #pragma unroll
    for (int off = 32; off >= 4; off >>= 1)
        loss += __shfl_down(loss, off);
    if (t == 0) out[0] = loss * (1.0f / (float)B_);
}

extern "C" void kernel_launch(void* const* d_in, const int* in_sizes, int n_in,
                              void* d_out, int out_size, void* d_ws, size_t ws_size,
                              hipStream_t stream) {
    const float* pred = (const float*)d_in[0];
    const float* mask = (const float*)d_in[1];
    float* out = (float*)d_out;
    float* partial = (float*)d_ws;      // 1024*4 floats, fully overwritten each call

    dim3 grid(W_ / TW, H_ / TH, B_);    // 8 x 8 x 16 = 1024 blocks
    structure_loss_tile<<<grid, NTHR, 0, stream>>>(pred, mask, partial);
    structure_loss_final<<<1, 64, 0, stream>>>(partial, out);
}